// Round 4
// baseline (649.012 us; speedup 1.0000x reference)
//
#include <hip/hip_runtime.h>

// DynamicFilter: out[b,c,h,w] = sum_p (y[c*9+p] + bias[c*9+p]) * x[b,c,h+dh,w+dw]
//   y[o] = sum_c' x[b,c',h,w] * W[o,c']   (GEMM M=65536, N=2304, K=256, bf16 MFMA)
// B=4, C=256, H=W=128, 9 taps.
// R6: ring-of-3 pipelined staging, counted vmcnt, drain-barriers ("s_waitcnt
//   vmcnt(N) lgkmcnt(0); s_barrier" single asm blob). 150 us, but occupancy
//   still 2 blocks/CU: regs (afr 64 + acc 72 + ~48 temps = 184 > 512/3) AND
//   LDS (58368) both bind.
// R7: (a) Y pitch 20 -> 16 with XOR swizzle col' = col ^ ((o&3)<<2): b128
//   writes uniform 8/bank, scalar reads exactly 2/bank (wave-b32 minimum;
//   old pattern was 3-way) -> Y 11520 -> 9216 B/wave, LDS 58368 -> 49152
//   (<= 53.3K: 3 blocks/CU). Y still avoids buf0 so the cross-epilogue sub0
//   prefetch survives. (b) __launch_bounds__(256,3) to force combined regs
//   <= ~168 so 3 waves/SIMD is actually granted.

typedef __attribute__((ext_vector_type(8))) short bf16x8;   // 8 bf16 = 4 VGPRs
typedef __attribute__((ext_vector_type(4))) float f32x4;    // MFMA 16x16 acc

__device__ __forceinline__ unsigned int f2bf(float f) {
    unsigned int u = __float_as_uint(f);
    return (u + 0x7fffu + ((u >> 16) & 1u)) >> 16;   // RNE
}
__device__ __forceinline__ unsigned int pack2(float a, float b) {
    return f2bf(a) | (f2bf(b) << 16);
}

// ---------------------------------------------------------------------------
// Kernel 1: W (2304x256 fp32) -> Wb bf16, k-half-major:
//   Wb[kh][o][16 groups of 8 k], gs = ((gh&7)^(o&7)) | (gh&8)
// ---------------------------------------------------------------------------
__global__ __launch_bounds__(256) void wconv_kernel(const float* __restrict__ W,
                                                    unsigned char* __restrict__ Wb) {
    int idx = blockIdx.x * 256 + threadIdx.x;    // 73728 = 2304 * 32 groups
    int o = idx >> 5, g = idx & 31;
    const float4* src = (const float4*)(W + ((size_t)o << 8) + ((size_t)g << 3));
    float4 v0 = src[0], v1 = src[1];
    uint4 pk;
    pk.x = pack2(v0.x, v0.y); pk.y = pack2(v0.z, v0.w);
    pk.z = pack2(v1.x, v1.y); pk.w = pack2(v1.z, v1.w);
    int kh = g >> 4, gh = g & 15;
    int gs = ((gh & 7) ^ (o & 7)) | (gh & 8);
    size_t dst = (size_t)kh * 589824 + (size_t)o * 256 + ((size_t)gs << 4);
    *(uint4*)(Wb + dst) = pk;
}

// ---------------------------------------------------------------------------
// Kernel 2: fused GEMM + epilogue, ring-3 pipelined staging.
// LDS map: bufs 0,1,2 at 0/12288/24576 (12288 B each); per-wave Y (9216 B,
// pitch 16 dwords, XOR-swizzled) at 12288 + wv*9216 (aliases bufs 1,2 plus
// 12288 beyond; never buf0). Total 49152 B -> 3 blocks/CU (with reg fit).
// Sub-tile j (0..5): kh = j/3, ni-block = (j%3)*3, ring buf = j%3.
// Phase table (stage-target vs read-buffer, never equal in one phase):
//   ph0: stage b1,b2 read b0 | ph1: stage b0 read b1 | ph2: stage b1 read b2
//   ph3: stage b2 read b0 | ph4: stage b0(next sub0) read b1 | ph5: read b2
// Y swizzle: logical Y[o][col], col=pixel 0..15; physical dword =
//   o*16 + (col ^ ((o&3)<<2)). XOR only touches bits 2-3 -> f32x4 writes stay
//   contiguous/aligned. Writes: start banks {0,4,8,12}+16*(o&1), 8 lanes each
//   -> uniform 8/bank. Reads (fixed p, quads give o,o+9,o+18,o+27): two quads
//   per 16-bank half, each covering it bijectively -> 2/bank (minimum).
// ---------------------------------------------------------------------------

// Drain-barrier: wave's LDS ops complete before the HW barrier; vmcnt counted
// (N in flight allowed). Single asm blob = compiler memory fence, no seams.
#define SYNC_VM(N) asm volatile("s_waitcnt vmcnt(" #N ") lgkmcnt(0)\n\ts_barrier" ::: "memory")
#define SYNC_LG    asm volatile("s_waitcnt lgkmcnt(0)\n\ts_barrier" ::: "memory")
#define WAIT_LGKM0 asm volatile("s_waitcnt lgkmcnt(0)" ::: "memory")

// Stage sub-tile J of chunk CH into ring buf J%3. Each wave stages its
// 3072-B quarter with 3 x global_load_lds(16B): per-wave vmcnt += 3.
#define STAGE(CH, J)                                                            \
    do {                                                                        \
        const unsigned char* bs_ = Wb + (size_t)((J) / 3) * 589824              \
            + (size_t)(CH) * 36864 + ((J) % 3) * 12288 + wv * 3072 + (lane << 4); \
        unsigned char* bd_ = smem + ((J) % 3) * 12288 + wv * 3072;              \
        _Pragma("unroll")                                                       \
        for (int c_ = 0; c_ < 3; ++c_)                                          \
            __builtin_amdgcn_global_load_lds(                                   \
                (const __attribute__((address_space(1))) void*)(bs_ + c_ * 1024), \
                (__attribute__((address_space(3))) void*)(bd_ + c_ * 1024), 16, 0, 0); \
    } while (0)

// 24 MFMAs on sub-tile J (3 ni x 2 mi x 4 s): 6 independent acc chains per s.
#define MFMA_SUB(J)                                                             \
    do {                                                                        \
        const int kh_ = (J) / 3, snib_ = ((J) % 3) * 3;                         \
        const unsigned char* bb_ = smem + ((J) % 3) * 12288;                    \
        _Pragma("unroll")                                                       \
        for (int s_ = 0; s_ < 4; ++s_) {                                        \
            const bf16x8 a0_ = afr[(kh_ << 2) + s_];                            \
            const bf16x8 a1_ = afr[8 + (kh_ << 2) + s_];                        \
            const int gb_ = (s_ << 2) + quad;                                   \
            _Pragma("unroll")                                                   \
            for (int ni_ = 0; ni_ < 3; ++ni_) {                                 \
                const bf16x8 bq_ = *(const bf16x8*)(                            \
                    bb_ + (((ni_ << 4) + lrow) << 8) + ((gb_ ^ swz) << 4));     \
                acc[0][snib_ + ni_] = __builtin_amdgcn_mfma_f32_16x16x32_bf16(  \
                    a0_, bq_, acc[0][snib_ + ni_], 0, 0, 0);                    \
                acc[1][snib_ + ni_] = __builtin_amdgcn_mfma_f32_16x16x32_bf16(  \
                    a1_, bq_, acc[1][snib_ + ni_], 0, 0, 0);                    \
            }                                                                   \
        }                                                                       \
    } while (0)

__global__ __launch_bounds__(256, 3) void dfgemm_kernel(
        const unsigned char* __restrict__ Wb, const float* __restrict__ x,
        const float* __restrict__ bias, float* __restrict__ out) {
    __shared__ __align__(16) unsigned char smem[49152];

    const int t = threadIdx.x;
    const int lane = t & 63, wv = t >> 6;
    const int quad = lane >> 4, lrow = lane & 15;
    const int swz = lrow & 7;

    const int b = blockIdx.x >> 7;               // image 0..3
    const int h = blockIdx.x & 127;              // row

    // Warm the pipeline: chunk 0 subs 0,1,2 in flight while afr loads run.
    STAGE(0, 0); STAGE(0, 1); STAGE(0, 2);

    // ---- A fragments direct from x: afr[mi*8+gg][j] = bf16(x[b, gg*32+quad*8+j, h, w]) ----
    bf16x8 afr[16];
    {
        const float* xrow = x + ((size_t)b << 22) + (h << 7);
        #pragma unroll
        for (int mi = 0; mi < 2; ++mi) {
            const int w = (wv << 5) + (mi << 4) + lrow;
            #pragma unroll
            for (int gg = 0; gg < 8; ++gg) {
                const float* p = xrow + ((size_t)((gg << 5) + (quad << 3)) << 14) + w;
                float v[8];
                #pragma unroll
                for (int e = 0; e < 8; ++e) v[e] = p[(size_t)e << 14];
                uint4 pk;
                pk.x = pack2(v[0], v[1]); pk.y = pack2(v[2], v[3]);
                pk.z = pack2(v[4], v[5]); pk.w = pack2(v[6], v[7]);
                afr[(mi << 3) + gg] = *(const bf16x8*)&pk;
            }
        }
    }
    SYNC_VM(0);                        // prologue only: subs 0-2 landed, full drain

    #pragma unroll 1
    for (int chunk = 0; chunk < 16; ++chunk) {
        f32x4 acc[2][9];
        const f32x4 zero = {0.f, 0.f, 0.f, 0.f};
        #pragma unroll
        for (int mi = 0; mi < 2; ++mi)
            #pragma unroll
            for (int ni = 0; ni < 9; ++ni) acc[mi][ni] = zero;

        // Counted-vmcnt bookkeeping (in-order retirement): phase-t sync
        // retires sub-t while the newer stage stays in flight.
        // Loop top: worst case outstanding = [3 sub0 loads][<=8 out-stores];
        // vmcnt(8) retires to <=8 -> sub0 (older) necessarily retired.
        SYNC_VM(8);                            // sub0 ready; all waves past Y reads
        if (chunk) { STAGE(chunk, 1); STAGE(chunk, 2); }   // into bufs 1,2 (ex-Y)
        MFMA_SUB(0);

        SYNC_VM(3);                            // sub1 landed (sub2 may fly)
        STAGE(chunk, 3);                       // buf0 (sub0 readers drained)
        MFMA_SUB(1);

        SYNC_VM(3);                            // sub2 landed (sub3 may fly)
        STAGE(chunk, 4);                       // buf1
        MFMA_SUB(2);

        SYNC_VM(3);                            // sub3 landed
        STAGE(chunk, 5);                       // buf2
        MFMA_SUB(3);

        SYNC_VM(3);                            // sub4 landed
        STAGE((chunk + 1) & 15, 0);            // next chunk sub0 -> buf0 (Y-safe)
        MFMA_SUB(4);

        SYNC_VM(3);                            // sub5 landed (next-sub0 may fly)
        MFMA_SUB(5);

        SYNC_LG;                               // bufs 1,2 reads drained -> Y-safe

        // ---- epilogue: per-wave Y [144 out][16-dword pitch, XOR-swizzled] ----
        float* Y = (float*)(smem + 12288 + wv * 9216);
        #pragma unroll
        for (int half = 0; half < 2; ++half) {
            #pragma unroll
            for (int ni = 0; ni < 9; ++ni) {
                const int o = (ni << 4) + lrow;          // o&3 == lrow&3
                *(f32x4*)(Y + (o << 4) + ((quad ^ (lrow & 3)) << 2)) = acc[half][ni];
            }
            WAIT_LGKM0;                        // wave-local LDS RAW (no vm drain)

            const int w = (wv << 5) + (half << 4) + lrow;    // this lane's pixel
            #pragma unroll
            for (int it = 0; it < 4; ++it) {
                const int cgl = (it << 2) + quad;            // 0..15
                const int cg = (chunk << 4) + cgl;           // channel 0..255
                const int ob = cgl * 9;                      // first out row
                const float* bp = bias + cg * 9;
                const float* xc = x + ((size_t)((b << 8) + cg) << 14);
                float sum = 0.f;
                #pragma unroll
                for (int p = 0; p < 9; ++p) {
                    const int o = ob + p;
                    const float yv = Y[(o << 4) + (lrow ^ ((o & 3) << 2))];
                    const int hh = h + p / 3 - 1, ww = w + p % 3 - 1;
                    float xv = 0.f;
                    if ((unsigned)hh < 128u && (unsigned)ww < 128u)
                        xv = xc[(hh << 7) + ww];             // fp32 patch
                    sum += (yv + bp[p]) * xv;
                }
                out[((size_t)((b << 8) + cg) << 14) + (h << 7) + w] = sum;
            }
        }
    }
}

extern "C" void kernel_launch(void* const* d_in, const int* in_sizes, int n_in,
                              void* d_out, int out_size, void* d_ws, size_t ws_size,
                              hipStream_t stream) {
    const float* x    = (const float*)d_in[0];   // 4*256*128*128
    const float* W    = (const float*)d_in[1];   // 2304*256
    const float* bias = (const float*)d_in[2];   // 2304
    float* out = (float*)d_out;

    unsigned char* Wb = (unsigned char*)d_ws;    // 1,179,648 B

    wconv_kernel<<<288, 256, 0, stream>>>(W, Wb);
    dfgemm_kernel<<<512, 256, 0, stream>>>(Wb, x, bias, out);
}

// Round 6
// 225.215 us; speedup vs baseline: 2.8817x; 2.8817x over previous
//
#include <hip/hip_runtime.h>

// DynamicFilter: out[b,c,h,w] = sum_p (y[c*9+p] + bias[c*9+p]) * x[b,c,h+dh,w+dw]
//   y[o] = sum_c' x[b,c',h,w] * W[o,c']   (GEMM M=65536, N=2304, K=256, bf16 MFMA)
// B=4, C=256, H=W=128, 9 taps.
// R6 (green, 150us): ring-3, counted vmcnt, drain-barriers. R7: (256,3)
//   spilled -> 567us. R8: 512-thr/8-wave, ring-4 + dedicated Y -> NaN.
// R9 = R8 with the two unverified primitives removed:
//   (a) 12-B global_load_lds (stride semantics unverified on gfx950) ->
//       16-B only: sub-tile = 6 slices x 2048 B, wave wv stages slice wv%6
//       with 2 x 16B DMA; waves 6,7 duplicate slices 0,1 (same bytes, benign
//       write-write race; vmcnt increment stays wave-uniform at +2 so all R8
//       SYNC counts remain valid).
//   (b) pre-epilogue STAGE could be compiler-sunk past the epilogue's patch
//       loads (intrinsic vs load, provably no-alias) breaking the
//       "consumed-patch-loads force-retire the stage" argument -> zero-cost
//       asm "" memory fence pins it.
// Structure: grid 256 x 512 thr (1 block/CU, 2 rows, 8 waves). Ring-4 bufs
// (49152) + DEDICATED per-wave Y (8 x 9216) = 122880 B LDS. Y never aliases
// the ring -> barrier-free epilogue. Waits: VM(8) ph0-3 (needed subs
// force-retired by consumed patch loads; bounds out-stores only), VM(4)
// ph4/5 (exactly the 2 younger 2-load stages). No vmcnt(0) in steady state.
// Buf WAR chains (reader -> draining barrier -> next writer):
//   buf0: sub0 -> M0/ph1 -> st4; sub4 -> M4/ph5 -> st0'
//   buf1: sub1 -> M1/ph2 -> st5; sub5 -> M5/SYNC_LG -> st1'
//   buf2: sub2 -> M2/ph3 -> st2'    buf3: sub3 -> M3/ph4 -> st3'

typedef __attribute__((ext_vector_type(8))) short bf16x8;   // 8 bf16 = 4 VGPRs
typedef __attribute__((ext_vector_type(4))) float f32x4;    // MFMA 16x16 acc

__device__ __forceinline__ unsigned int f2bf(float f) {
    unsigned int u = __float_as_uint(f);
    return (u + 0x7fffu + ((u >> 16) & 1u)) >> 16;   // RNE
}
__device__ __forceinline__ unsigned int pack2(float a, float b) {
    return f2bf(a) | (f2bf(b) << 16);
}

// ---------------------------------------------------------------------------
// Kernel 1: W (2304x256 fp32) -> Wb bf16, k-half-major:
//   Wb[kh][o][16 groups of 8 k], gs = ((gh&7)^(o&7)) | (gh&8)
// ---------------------------------------------------------------------------
__global__ __launch_bounds__(256) void wconv_kernel(const float* __restrict__ W,
                                                    unsigned char* __restrict__ Wb) {
    int idx = blockIdx.x * 256 + threadIdx.x;    // 73728 = 2304 * 32 groups
    int o = idx >> 5, g = idx & 31;
    const float4* src = (const float4*)(W + ((size_t)o << 8) + ((size_t)g << 3));
    float4 v0 = src[0], v1 = src[1];
    uint4 pk;
    pk.x = pack2(v0.x, v0.y); pk.y = pack2(v0.z, v0.w);
    pk.z = pack2(v1.x, v1.y); pk.w = pack2(v1.z, v1.w);
    int kh = g >> 4, gh = g & 15;
    int gs = ((gh & 7) ^ (o & 7)) | (gh & 8);
    size_t dst = (size_t)kh * 589824 + (size_t)o * 256 + ((size_t)gs << 4);
    *(uint4*)(Wb + dst) = pk;
}

// ---------------------------------------------------------------------------
// Kernel 2. LDS map: ring bufs 0..3 at 0/12288/24576/36864; per-wave Y
// (9216 B, pitch 16 dwords, XOR-swizzled) at 49152 + wv*9216. Total 122880.
// Sub-tile j (0..5): kh = j/3, ni-block = j%3, ring buf = j%4.
// ---------------------------------------------------------------------------

// Drain-barrier: wave's LDS ops complete before the HW barrier; vmcnt counted
// (N in flight allowed). Single asm blob = compiler memory fence, no seams.
#define SYNC_VM(N) asm volatile("s_waitcnt vmcnt(" #N ") lgkmcnt(0)\n\ts_barrier" ::: "memory")
#define SYNC_LG    asm volatile("s_waitcnt lgkmcnt(0)\n\ts_barrier" ::: "memory")
#define WAIT_LGKM0 asm volatile("s_waitcnt lgkmcnt(0)" ::: "memory")
#define FENCE      asm volatile("" ::: "memory")   // compile-time order pin only

// Stage sub-tile J of chunk CH into ring buf J%4. Slices of 2048 B; wave wv
// stages slice wv%6 with 2 x global_load_lds(16B); waves 6,7 duplicate
// slices 0,1 (identical bytes). Per-wave vmcnt += 2, uniform across waves.
#define STAGE(CH, J)                                                            \
    do {                                                                        \
        const int sl_ = (wv < 6) ? wv : (wv - 6);                               \
        const unsigned char* bs_ = Wb + (size_t)((J) / 3) * 589824              \
            + (size_t)(CH) * 36864 + ((J) % 3) * 12288 + sl_ * 2048 + (lane << 4); \
        unsigned char* bd_ = smem + ((J) % 4) * 12288 + sl_ * 2048;             \
        __builtin_amdgcn_global_load_lds(                                       \
            (const __attribute__((address_space(1))) void*)(bs_),               \
            (__attribute__((address_space(3))) void*)(bd_), 16, 0, 0);          \
        __builtin_amdgcn_global_load_lds(                                       \
            (const __attribute__((address_space(1))) void*)(bs_ + 1024),        \
            (__attribute__((address_space(3))) void*)(bd_ + 1024), 16, 0, 0);   \
    } while (0)

// 24 MFMAs on sub-tile J (3 ni x 2 mi x 4 s): 6 independent acc chains per s.
#define MFMA_SUB(J)                                                             \
    do {                                                                        \
        const int kh_ = (J) / 3, snib_ = ((J) % 3) * 3;                         \
        const unsigned char* bb_ = smem + ((J) % 4) * 12288;                    \
        _Pragma("unroll")                                                       \
        for (int s_ = 0; s_ < 4; ++s_) {                                        \
            const bf16x8 a0_ = afr[(kh_ << 2) + s_];                            \
            const bf16x8 a1_ = afr[8 + (kh_ << 2) + s_];                        \
            const int gb_ = (s_ << 2) + quad;                                   \
            _Pragma("unroll")                                                   \
            for (int ni_ = 0; ni_ < 3; ++ni_) {                                 \
                const bf16x8 bq_ = *(const bf16x8*)(                            \
                    bb_ + (((ni_ << 4) + lrow) << 8) + ((gb_ ^ swz) << 4));     \
                acc[0][snib_ + ni_] = __builtin_amdgcn_mfma_f32_16x16x32_bf16(  \
                    a0_, bq_, acc[0][snib_ + ni_], 0, 0, 0);                    \
                acc[1][snib_ + ni_] = __builtin_amdgcn_mfma_f32_16x16x32_bf16(  \
                    a1_, bq_, acc[1][snib_ + ni_], 0, 0, 0);                    \
            }                                                                   \
        }                                                                       \
    } while (0)

__global__ __launch_bounds__(512, 2) void dfgemm_kernel(
        const unsigned char* __restrict__ Wb, const float* __restrict__ x,
        const float* __restrict__ bias, float* __restrict__ out) {
    __shared__ __align__(16) unsigned char smem[122880];

    const int t = threadIdx.x;
    const int lane = t & 63, wv = t >> 6;        // wv 0..7
    const int quad = lane >> 4, lrow = lane & 15;
    const int swz = lrow & 7;

    const int b = blockIdx.x >> 6;               // image 0..3
    const int hp = blockIdx.x & 63;              // row pair
    const int h = (hp << 1) + (wv >> 2);         // this wave's row
    const int wq = wv & 3;                       // px quarter within the row

    // Warm the pipeline: chunk 0 subs 0..3 in flight while afr loads run.
    STAGE(0, 0); STAGE(0, 1); STAGE(0, 2); STAGE(0, 3);

    // ---- A fragments direct from x: afr[mi*8+gg][j] = bf16(x[b, gg*32+quad*8+j, h, w]) ----
    bf16x8 afr[16];
    {
        const float* xrow = x + ((size_t)b << 22) + (h << 7);
        #pragma unroll
        for (int mi = 0; mi < 2; ++mi) {
            const int w = (wq << 5) + (mi << 4) + lrow;
            #pragma unroll
            for (int gg = 0; gg < 8; ++gg) {
                const float* p = xrow + ((size_t)((gg << 5) + (quad << 3)) << 14) + w;
                float v[8];
                #pragma unroll
                for (int e = 0; e < 8; ++e) v[e] = p[(size_t)e << 14];
                uint4 pk;
                pk.x = pack2(v[0], v[1]); pk.y = pack2(v[2], v[3]);
                pk.z = pack2(v[4], v[5]); pk.w = pack2(v[6], v[7]);
                afr[(mi << 3) + gg] = *(const bf16x8*)&pk;
            }
        }
    }
    SYNC_VM(0);                        // prologue only: subs 0-3 landed, full drain

    #pragma unroll 1
    for (int chunk = 0; chunk < 16; ++chunk) {
        const int c1 = (chunk + 1) & 15;         // tail wraps: harmless re-stage
        f32x4 acc[2][9];
        const f32x4 zero = {0.f, 0.f, 0.f, 0.f};
        #pragma unroll
        for (int mi = 0; mi < 2; ++mi)
            #pragma unroll
            for (int ni = 0; ni < 9; ++ni) acc[mi][ni] = zero;

        // ph0: sub0 (staged ph5 prev) force-retired by the epilogue's
        // consumed patch loads; VM(8) only bounds the <=8 out-stores.
        SYNC_VM(8);
        MFMA_SUB(0);

        SYNC_VM(8);                            // ph1: sub1 (pre-epi, FENCEd) retired
        STAGE(chunk, 4);                       // buf0 (sub0 readers drained)
        MFMA_SUB(1);

        SYNC_VM(8);                            // ph2: sub2 (ph3 prev) retired
        STAGE(chunk, 5);                       // buf1
        MFMA_SUB(2);

        SYNC_VM(8);                            // ph3: sub3 (ph4 prev) retired
        STAGE(c1, 2);                          // buf2
        MFMA_SUB(3);

        SYNC_VM(4);                            // ph4: retire sub4 (ph1); keep ph2+ph3
        STAGE(c1, 3);                          // buf3
        MFMA_SUB(4);

        SYNC_VM(4);                            // ph5: retire sub5 (ph2); keep ph3+ph4
        STAGE(c1, 0);                          // buf0 (sub4 readers drained)
        MFMA_SUB(5);

        SYNC_LG;                               // all M5 buf1 reads drained
        STAGE(c1, 1);                          // buf1; lands during epilogue
        FENCE;                                 // pin stage BEFORE patch loads/stores

        // ---- epilogue: per-wave Y [144 out][16-dword pitch, XOR-swizzled],
        //      dedicated region -> no barriers, no vm drains ----
        float* Y = (float*)(smem + 49152 + wv * 9216);
        #pragma unroll
        for (int half = 0; half < 2; ++half) {
            #pragma unroll
            for (int ni = 0; ni < 9; ++ni) {
                const int o = (ni << 4) + lrow;          // o&3 == lrow&3
                *(f32x4*)(Y + (o << 4) + ((quad ^ (lrow & 3)) << 2)) = acc[half][ni];
            }
            WAIT_LGKM0;                        // wave-local LDS RAW

            const int w = (wq << 5) + (half << 4) + lrow;    // this lane's pixel
            #pragma unroll
            for (int it = 0; it < 4; ++it) {
                const int cgl = (it << 2) + quad;            // 0..15
                const int cg = (chunk << 4) + cgl;           // channel 0..255
                const int ob = cgl * 9;                      // first out row
                const float* bp = bias + cg * 9;
                const float* xc = x + ((size_t)((b << 8) + cg) << 14);
                float sum = 0.f;
                #pragma unroll
                for (int p = 0; p < 9; ++p) {
                    const int o = ob + p;
                    const float yv = Y[(o << 4) + (lrow ^ ((o & 3) << 2))];
                    const int hh = h + p / 3 - 1, ww = w + p % 3 - 1;
                    float xv = 0.f;
                    if ((unsigned)hh < 128u && (unsigned)ww < 128u)
                        xv = xc[(hh << 7) + ww];             // fp32 patch
                    sum += (yv + bp[p]) * xv;
                }
                out[((size_t)((b << 8) + cg) << 14) + (h << 7) + w] = sum;
            }
        }
    }
}

extern "C" void kernel_launch(void* const* d_in, const int* in_sizes, int n_in,
                              void* d_out, int out_size, void* d_ws, size_t ws_size,
                              hipStream_t stream) {
    const float* x    = (const float*)d_in[0];   // 4*256*128*128
    const float* W    = (const float*)d_in[1];   // 2304*256
    const float* bias = (const float*)d_in[2];   // 2304
    float* out = (float*)d_out;

    unsigned char* Wb = (unsigned char*)d_ws;    // 1,179,648 B

    wconv_kernel<<<288, 256, 0, stream>>>(W, Wb);
    dfgemm_kernel<<<256, 512, 0, stream>>>(Wb, x, bias, out);
}